// Round 16
// baseline (247.960 us; speedup 1.0000x reference)
//
#include <hip/hip_runtime.h>
#include <hip/hip_bf16.h>
#include <math.h>

typedef __bf16 bf16;
typedef __attribute__((ext_vector_type(8))) __bf16 bf16x8;
typedef __attribute__((ext_vector_type(4))) __bf16 bf16x4;
typedef __attribute__((ext_vector_type(4))) float  f32x4;

// ---- problem dims (fixed by reference) ----
static constexpr int Bsz = 2, L = 2048, DM = 1024, DI = 2048, DS = 16, DTR = 64;
static constexpr int M   = Bsz * L;        // 4096 tokens
static constexpr int NXZ = 2 * DI;         // 4096
static constexpr int NXD = DTR + 2 * DS;   // 96
static constexpr int NC  = 32;             // scan chunks
static constexpr int CL  = L / NC;         // 64 steps per chunk
static constexpr int KS  = 8;              // x_proj K-splits
static constexpr float LOG2E = 1.4426950408889634f;

// raw v_exp_f32 (trans pipe), no OCML wrapper
__device__ inline float ex2(float x) { return __builtin_amdgcn_exp2f(x); }

__device__ inline void gload_lds16(const void* g, void* l)
{
    __builtin_amdgcn_global_load_lds(
        (const __attribute__((address_space(1))) void*)g,
        (__attribute__((address_space(3))) void*)l, 16, 0, 0);
}

#define SBAR() { asm volatile("" ::: "memory"); __builtin_amdgcn_s_barrier(); asm volatile("" ::: "memory"); }
#define VMCNT12() asm volatile("s_waitcnt vmcnt(12)" ::: "memory")
#define VMCNT9()  asm volatile("s_waitcnt vmcnt(9)" ::: "memory")
#define VMCNT8()  asm volatile("s_waitcnt vmcnt(8)" ::: "memory")
#define VMCNT6()  asm volatile("s_waitcnt vmcnt(6)" ::: "memory")
#define VMCNT4()  asm volatile("s_waitcnt vmcnt(4)" ::: "memory")
#define VMCNT3()  asm volatile("s_waitcnt vmcnt(3)" ::: "memory")
#define VMCNT0()  asm volatile("s_waitcnt vmcnt(0)" ::: "memory")

// Additive LDS k-slot swizzle (conflict-free in every 8-lane read group):
//  stage source slot for thread: ((tid&3) - ((tid>>3)&3)) & 3
//  read position for (ko16, fr): (ko16 + ((fr>>1)&3)) & 3

// ============================================================================
// Fused fp32 -> bf16 cast of all 5 tensors (one launch, float4 granularity).
// ============================================================================
static constexpr int C0 = M * DM / 4;            // x
static constexpr int C1 = C0 + NXZ * DM / 4;     // in_w
static constexpr int C2 = C1 + DM * DI / 4;      // out_w
static constexpr int C3 = C2 + NXD * DI / 4;     // xp_w
static constexpr int C4 = C3 + DI * DTR / 4;     // dt_w

__global__ __launch_bounds__(256)
void cast_all(const float* __restrict__ s0, const float* __restrict__ s1,
              const float* __restrict__ s2, const float* __restrict__ s3,
              const float* __restrict__ s4,
              bf16* __restrict__ d0, bf16* __restrict__ d1,
              bf16* __restrict__ d2, bf16* __restrict__ d3,
              bf16* __restrict__ d4)
{
    const int i = blockIdx.x * 256 + threadIdx.x;
    const float* s; bf16* d; int off;
    if      (i < C0) { s = s0; d = d0; off = 0;  }
    else if (i < C1) { s = s1; d = d1; off = C0; }
    else if (i < C2) { s = s2; d = d2; off = C1; }
    else if (i < C3) { s = s3; d = d3; off = C2; }
    else             { s = s4; d = d4; off = C3; }
    const int j = i - off;
    float4 v = ((const float4*)s)[j];
    bf16x4 o = {(bf16)v.x, (bf16)v.y, (bf16)v.z, (bf16)v.w};
    ((bf16x4*)d)[j] = o;
}

// ============================================================================
// 256x256 8-phase bf16 MFMA GEMM for in_proj (M=4096, N=4096, K=1024).
// ============================================================================
static constexpr int GK  = DM;        // 1024
static constexpr int GNT = GK / 64;   // 16 K-tiles

__device__ __forceinline__ void stage_half(const bf16* __restrict__ Gbase, int ld,
                                           int kbase, bf16* lds_slot, int tid, int wid)
{
    const int rl = tid >> 2;                                      // 0..127
    const int ks = ((((tid & 3) - ((tid >> 3) & 3)) & 3) << 3);   // additive swizzle src
#pragma unroll
    for (int i = 0; i < 2; ++i)
        gload_lds16(Gbase + (size_t)(i * 128 + rl) * ld + kbase + ks,
                    lds_slot + i * 4096 + wid * 512);
}

template<int MH>
__device__ __forceinline__ void ldA4(const bf16* As, int abase, bf16x8 af[4])
{
#pragma unroll
    for (int mm = 0; mm < 4; ++mm)
        af[mm] = *(const bf16x8*)(As + abase + (MH * 4 + mm) * 512);
}

__device__ __forceinline__ void ldB4(const bf16* Bs, int bbase, bf16x8 bfr[4])
{
#pragma unroll
    for (int nn = 0; nn < 4; ++nn)
        bfr[nn] = *(const bf16x8*)(Bs + bbase + nn * 512);
}

template<int MH>
__device__ __forceinline__ void mfma16(f32x4 acc[8][4], const bf16x8 af[4],
                                       const bf16x8 bfr[4])
{
#pragma unroll
    for (int mm = 0; mm < 4; ++mm)
#pragma unroll
        for (int nn = 0; nn < 4; ++nn)
            acc[MH * 4 + mm][nn] = __builtin_amdgcn_mfma_f32_16x16x32_bf16(
                af[mm], bfr[nn], acc[MH * 4 + mm][nn], 0, 0, 0);
}

__global__ __launch_bounds__(512, 1)
void gemm256_inproj(const bf16* __restrict__ A, const bf16* __restrict__ Bw,
                    bf16* __restrict__ C)
{
    __shared__ __align__(16) bf16 Asl[4 * 8192];   // 64 KiB (4 slots [256][32])
    __shared__ __align__(16) bf16 Bsl[4 * 8192];   // 64 KiB

    const int tid  = threadIdx.x;
    const int wid  = tid >> 6;
    const int lane = tid & 63;
    const int wr   = wid >> 2;            // 0..1
    const int wc   = wid & 3;             // 0..3
    const int fr   = lane & 15;
    const int ko16 = lane >> 4;           // 0..3 (k 16B slot wanted)
    const int kx   = (((ko16 + ((fr >> 1) & 3)) & 3) << 3);   // swizzled read pos

    // XCD-aware bijective swizzle (256 blocks, 8 XCDs)
    const int bid = blockIdx.x;
    const int wg  = (bid & 7) * 32 + (bid >> 3);
    const int by  = wg >> 4, bx = wg & 15;
    const int row0 = by * 256, col0 = bx * 256;

    const bf16* Ablk = A  + (size_t)row0 * GK;
    const bf16* Bblk = Bw + (size_t)col0 * GK;

    const int abase = (wr * 128 + fr) * 32 + kx;
    const int bbase = (wc * 64 + fr) * 32 + kx;

    f32x4 acc[8][4] = {};
    bf16x8 af[4], bfr[4];

    // ---- prologue: stage t0 (h0,h1) + t1 (h0) = 12 gloads ----
    stage_half(Ablk, GK, 0,       Asl + 0 * 8192, tid, wid);   // t0 h0 -> slot0
    stage_half(Bblk, GK, 0,       Bsl + 0 * 8192, tid, wid);
    stage_half(Ablk, GK, 32,      Asl + 1 * 8192, tid, wid);   // t0 h1 -> slot1
    stage_half(Bblk, GK, 32,      Bsl + 1 * 8192, tid, wid);
    stage_half(Ablk, GK, 64,      Asl + 2 * 8192, tid, wid);   // t1 h0 -> slot2
    stage_half(Bblk, GK, 64,      Bsl + 2 * 8192, tid, wid);
    VMCNT4();          // t0 fully landed; t1-h0 (4 loads) in flight
    SBAR();

    for (int t = 0; t < GNT; ++t) {
        const int sk0 = (2 * t) & 3, sk1 = (2 * t + 1) & 3;
        const bf16* As0 = Asl + sk0 * 8192;
        const bf16* As1 = Asl + sk1 * 8192;
        const bf16* Bs0 = Bsl + sk0 * 8192;
        const bf16* Bs1 = Bsl + sk1 * 8192;

        // ---- phase 0: mh=0, ks=0 ----
        ldA4<0>(As0, abase, af);
        ldB4(Bs0, bbase, bfr);
        if (t + 1 < GNT)
            stage_half(Ablk, GK, (t + 1) * 64 + 32, Asl + ((2 * t + 3) & 3) * 8192, tid, wid);
        SBAR();
        __builtin_amdgcn_s_setprio(1);
        mfma16<0>(acc, af, bfr);
        __builtin_amdgcn_s_setprio(0);
        SBAR();

        // ---- phase 1: mh=1, ks=0 (B reuse) ----
        ldA4<1>(As0, abase, af);
        if (t + 1 < GNT)
            stage_half(Bblk, GK, (t + 1) * 64 + 32, Bsl + ((2 * t + 3) & 3) * 8192, tid, wid);
        SBAR();
        __builtin_amdgcn_s_setprio(1);
        mfma16<1>(acc, af, bfr);
        __builtin_amdgcn_s_setprio(0);
        SBAR();

        // ---- phase 2: mh=0, ks=1 ----
        ldA4<0>(As1, abase, af);
        ldB4(Bs1, bbase, bfr);
        if (t + 2 < GNT)
            stage_half(Ablk, GK, (t + 2) * 64, Asl + sk0 * 8192, tid, wid);
        SBAR();
        __builtin_amdgcn_s_setprio(1);
        mfma16<0>(acc, af, bfr);
        __builtin_amdgcn_s_setprio(0);
        SBAR();

        // ---- phase 3: mh=1, ks=1 (B reuse) ----
        ldA4<1>(As1, abase, af);
        if (t + 2 < GNT)
            stage_half(Bblk, GK, (t + 2) * 64, Bsl + sk0 * 8192, tid, wid);
        SBAR();
        __builtin_amdgcn_s_setprio(1);
        mfma16<1>(acc, af, bfr);
        __builtin_amdgcn_s_setprio(0);
        if (t < GNT - 3) { VMCNT4(); } else { VMCNT0(); }
        SBAR();
    }

    // ---- epilogue: C/D layout col=lane&15, row=(lane>>4)*4+reg ----
    const int r0 = row0 + wr * 128 + (ko16 << 2);
    const int c0 = col0 + wc * 64 + fr;
#pragma unroll
    for (int m = 0; m < 8; ++m)
#pragma unroll
        for (int n = 0; n < 4; ++n)
#pragma unroll
            for (int r = 0; r < 4; ++r)
                C[(size_t)(r0 + m * 16 + r) * NXZ + c0 + n * 16] = (bf16)acc[m][n][r];
}

// ============================================================================
// out_proj GEMM: out[M,1024] = y[M,2048] @ Wout[1024,2048]^T + x  (fp32 out).
// BM=128, BN=64, 512 blocks (2/CU), bijective XCD swizzle.
// 4-slot LDS ring, 3-deep prefetch, counted vmcnt(9/6/3/0).
// ============================================================================
__global__ __launch_bounds__(256)
void gemm_out(const bf16* __restrict__ A, const bf16* __restrict__ Bw,
              const float* __restrict__ res, float* __restrict__ Cout)
{
    __shared__ __align__(16) bf16 Asl[4][128 * 32];   // 4 x 8 KiB
    __shared__ __align__(16) bf16 Bsl[4][64 * 32];    // 4 x 4 KiB  (48 KiB total)

    const int tid  = threadIdx.x;
    const int bid  = blockIdx.x;
    const int orig = (bid & 7) * 64 + (bid >> 3);
    const int bx   = orig & 15;           // col block 0..15
    const int by   = orig >> 4;           // row block 0..31
    const int row0 = by * 128, col0 = bx * 64;

    const int w    = tid >> 6;
    const int lane = tid & 63;
    const int wr   = w >> 1, wc = w & 1;
    const int fr   = lane & 15;
    const int ko   = (((lane >> 4) + ((fr >> 1) & 3)) & 3) << 3;  // swizzled read

    f32x4 acc[4][2] = {};

    const int sr  = tid >> 2;             // 0..63
    const int ssk = ((((tid & 3) - ((tid >> 3) & 3)) & 3) << 3);  // swizzled src
    const bf16* gA0 = A  + (size_t)(row0 + sr) * NXZ + ssk;
    const bf16* gA1 = A  + (size_t)(row0 + 64 + sr) * NXZ + ssk;
    const bf16* gB0 = Bw + (size_t)(col0 + sr) * DI + ssk;

    const int NT = DI / 32;               // 64 K-iterations

#define STAGE_OUT(s, kk) do { \
        gload_lds16(gA0 + (kk), (char*)Asl[s] + w * 1024); \
        gload_lds16(gA1 + (kk), (char*)Asl[s] + 4096 + w * 1024); \
        gload_lds16(gB0 + (kk), (char*)Bsl[s] + w * 1024); } while (0)

    STAGE_OUT(0, 0);
    STAGE_OUT(1, 32);
    STAGE_OUT(2, 64);
    for (int i = 0; i < NT; ++i) {
        const int cur = i & 3;
        if (i + 3 < NT)      { STAGE_OUT((i + 3) & 3, (i + 3) * 32); VMCNT9(); }
        else if (i + 2 < NT) { VMCNT6(); }
        else if (i + 1 < NT) { VMCNT3(); }
        else                 { VMCNT0(); }
        SBAR();

        bf16x8 af[4], bfr[2];
#pragma unroll
        for (int m = 0; m < 4; ++m)
            af[m] = *(const bf16x8*)&Asl[cur][((wr << 6) + m * 16 + fr) * 32 + ko];
#pragma unroll
        for (int n = 0; n < 2; ++n)
            bfr[n] = *(const bf16x8*)&Bsl[cur][((wc << 5) + n * 16 + fr) * 32 + ko];
        __builtin_amdgcn_s_setprio(1);
#pragma unroll
        for (int m = 0; m < 4; ++m)
#pragma unroll
            for (int n = 0; n < 2; ++n)
                acc[m][n] = __builtin_amdgcn_mfma_f32_16x16x32_bf16(
                    af[m], bfr[n], acc[m][n], 0, 0, 0);
        __builtin_amdgcn_s_setprio(0);
        SBAR();
    }
#undef STAGE_OUT

    const int r0 = row0 + (wr << 6) + ((lane >> 4) << 2);
    const int c0 = col0 + (wc << 5) + fr;
#pragma unroll
    for (int m = 0; m < 4; ++m)
#pragma unroll
        for (int n = 0; n < 2; ++n)
#pragma unroll
            for (int r = 0; r < 4; ++r) {
                const int row = r0 + m * 16 + r;
                const int col = c0 + n * 16;
                Cout[(size_t)row * DM + col] =
                    acc[m][n][r] + res[(size_t)row * DM + col];
            }
}

// ============================================================================
// bf16 MFMA TN GEMM (128x128, 2-phase) — used for dt_proj (K=64, 2 iters).
// ============================================================================
template<int EPI>
__global__ __launch_bounds__(256)
void gemm_bf16(const bf16* __restrict__ A, const bf16* __restrict__ Bw,
               const float* __restrict__ bias, const float* __restrict__ res,
               void* __restrict__ Cout, int N, int K, int lda, int ldc)
{
    __shared__ __align__(16) bf16 Asl[128 * 32];
    __shared__ __align__(16) bf16 Bsl[128 * 32];

    const int tid  = threadIdx.x;
    const int row0 = blockIdx.y * 128;
    const int col0 = blockIdx.x * 128;
    const int w    = tid >> 6;
    const int lane = tid & 63;
    const int wr   = w >> 1, wc = w & 1;
    const int fr   = lane & 15;
    const int ko   = (((lane >> 4) + ((fr >> 1) & 3)) & 3) << 3;

    f32x4 acc[4][4] = {};

    const int sr  = tid >> 2;
    const int ssk = ((((tid & 3) - ((tid >> 3) & 3)) & 3) << 3);
    int brow0 = col0 + sr;       if (brow0 > N - 1) brow0 = N - 1;
    int brow1 = col0 + 64 + sr;  if (brow1 > N - 1) brow1 = N - 1;
    const bf16* gA0 = A  + (size_t)(row0 + sr) * lda + ssk;
    const bf16* gA1 = A  + (size_t)(row0 + 64 + sr) * lda + ssk;
    const bf16* gB0 = Bw + (size_t)brow0 * K + ssk;
    const bf16* gB1 = Bw + (size_t)brow1 * K + ssk;
    char* lA = (char*)Asl + w * 1024;
    char* lB = (char*)Bsl + w * 1024;

    for (int k0 = 0; k0 < K; k0 += 32) {
        gload_lds16(gA0 + k0, lA);
        gload_lds16(gA1 + k0, lA + 4096);
        gload_lds16(gB0 + k0, lB);
        gload_lds16(gB1 + k0, lB + 4096);
        __syncthreads();

        bf16x8 af[4], bfr[4];
#pragma unroll
        for (int m = 0; m < 4; ++m)
            af[m] = *(const bf16x8*)&Asl[((wr << 6) + m * 16 + fr) * 32 + ko];
#pragma unroll
        for (int n = 0; n < 4; ++n)
            bfr[n] = *(const bf16x8*)&Bsl[((wc << 6) + n * 16 + fr) * 32 + ko];
#pragma unroll
        for (int m = 0; m < 4; ++m)
#pragma unroll
            for (int n = 0; n < 4; ++n)
                acc[m][n] = __builtin_amdgcn_mfma_f32_16x16x32_bf16(
                    af[m], bfr[n], acc[m][n], 0, 0, 0);
        __syncthreads();
    }

    const int r0 = row0 + (wr << 6) + ((lane >> 4) << 2);
    const int c0 = col0 + (wc << 6) + fr;
#pragma unroll
    for (int m = 0; m < 4; ++m) {
#pragma unroll
        for (int n = 0; n < 4; ++n) {
            const int col = c0 + n * 16;
            if (col < N) {
#pragma unroll
                for (int r = 0; r < 4; ++r) {
                    const int row = r0 + m * 16 + r;
                    float v = acc[m][n][r];
                    if (EPI == 1) {
                        v += bias[col];
                        v = (v > 20.f) ? v : log1pf(expf(v));
                        ((bf16*)Cout)[(size_t)row * ldc + col] = (bf16)v;
                    } else {
                        ((bf16*)Cout)[(size_t)row * ldc + col] = (bf16)v;
                    }
                }
            }
        }
    }
}

// ============================================================================
// x_proj split-K GEMM: 4-slot ring, 3-deep prefetch, vmcnt(12/8/4/0).
// ============================================================================
__global__ __launch_bounds__(256)
void gemm_xproj(const bf16* __restrict__ A, const bf16* __restrict__ Bw,
                float* __restrict__ Cpart)
{
    __shared__ __align__(16) bf16 Asl[4][128 * 32];   // 32 KiB
    __shared__ __align__(16) bf16 Bsl[4][128 * 32];   // 32 KiB

    const int tid  = threadIdx.x;
    const int row0 = blockIdx.x * 128;
    const int kz   = blockIdx.y;
    const int kb   = kz * (2048 / KS);
    const int w    = tid >> 6;
    const int lane = tid & 63;
    const int wr   = w >> 1, wc = w & 1;
    const int fr   = lane & 15;
    const int ko   = (((lane >> 4) + ((fr >> 1) & 3)) & 3) << 3;

    f32x4 acc[4][4] = {};

    const int sr  = tid >> 2;
    const int ssk = ((((tid & 3) - ((tid >> 3) & 3)) & 3) << 3);
    int brow0 = sr;       if (brow0 > 95) brow0 = 95;
    int brow1 = 64 + sr;  if (brow1 > 95) brow1 = 95;
    const bf16* gA0 = A  + (size_t)(row0 + sr) * DI + kb + ssk;
    const bf16* gA1 = A  + (size_t)(row0 + 64 + sr) * DI + kb + ssk;
    const bf16* gB0 = Bw + (size_t)brow0 * DI + kb + ssk;
    const bf16* gB1 = Bw + (size_t)brow1 * DI + kb + ssk;

    const int NT = (2048 / KS) / 32;      // 8 K-iterations

#define STAGE_XP(s, kk) do { \
        gload_lds16(gA0 + (kk), (char*)Asl[s] + w * 1024); \
        gload_lds16(gA1 + (kk), (char*)Asl[s] + 4096 + w * 1024); \
        gload_lds16(gB0 + (kk), (char*)Bsl[s] + w * 1024); \
        gload_lds16(gB1 + (kk), (char*)Bsl[s] + 4096 + w * 1024); } while (0)

    STAGE_XP(0, 0);
    STAGE_XP(1, 32);
    STAGE_XP(2, 64);
    for (int i = 0; i < NT; ++i) {
        const int cur = i & 3;
        if (i + 3 < NT)      { STAGE_XP((i + 3) & 3, (i + 3) * 32); VMCNT12(); }
        else if (i + 2 < NT) { VMCNT8(); }
        else if (i + 1 < NT) { VMCNT4(); }
        else                 { VMCNT0(); }
        SBAR();

        bf16x8 af[4], bfr[4];
#pragma unroll
        for (int m = 0; m < 4; ++m)
            af[m] = *(const bf16x8*)&Asl[cur][((wr << 6) + m * 16 + fr) * 32 + ko];
#pragma unroll
        for (int n = 0; n < 4; ++n)
            bfr[n] = *(const bf16x8*)&Bsl[cur][((wc << 6) + n * 16 + fr) * 32 + ko];
        __builtin_amdgcn_s_setprio(1);
#pragma unroll
        for (int m = 0; m < 4; ++m)
#pragma unroll
            for (int n = 0; n < 4; ++n)
                acc[m][n] = __builtin_amdgcn_mfma_f32_16x16x32_bf16(
                    af[m], bfr[n], acc[m][n], 0, 0, 0);
        __builtin_amdgcn_s_setprio(0);
        SBAR();
    }
#undef STAGE_XP

    const int r0 = (wr << 6) + ((lane >> 4) << 2);
    const int c0 = (wc << 6) + fr;
    float* Cp = Cpart + (size_t)kz * M * 96 + (size_t)row0 * 96;
#pragma unroll
    for (int m = 0; m < 4; ++m) {
#pragma unroll
        for (int n = 0; n < 4; ++n) {
            const int col = c0 + n * 16;
            if (col < 96) {
#pragma unroll
                for (int r = 0; r < 4; ++r)
                    Cp[(size_t)(r0 + m * 16 + r) * 96 + col] = acc[m][n][r];
            }
        }
    }
}

__global__ __launch_bounds__(256)
void reduce_xdbl(const float* __restrict__ part, bf16* __restrict__ xdb)
{
    const int i = blockIdx.x * 256 + threadIdx.x;
    if (i >= M * 96) return;
    float s = 0.f;
#pragma unroll
    for (int k = 0; k < KS; ++k) s += part[(size_t)k * M * 96 + i];
    xdb[i] = (bf16)s;
}

// ============================================================================
// Causal depthwise conv1d (d_conv=4) + bias + SiLU.
// ============================================================================
__global__ __launch_bounds__(256)
void conv_silu(const bf16* __restrict__ xzb, const float* __restrict__ cw,
               const float* __restrict__ cb, bf16* __restrict__ u)
{
    const int idx = blockIdx.x * 256 + threadIdx.x;
    const int e   = (idx & 255) * 8;
    const int m   = idx >> 8;
    const int l   = m & (L - 1);

    float wv[8][4];
#pragma unroll
    for (int c = 0; c < 8; ++c) {
        float4 t = *(const float4*)(cw + (size_t)(e + c) * 4);
        wv[c][0] = t.x; wv[c][1] = t.y; wv[c][2] = t.z; wv[c][3] = t.w;
    }
    float acc[8];
    {
        float4 b0 = *(const float4*)(cb + e);
        float4 b1 = *(const float4*)(cb + e + 4);
        acc[0] = b0.x; acc[1] = b0.y; acc[2] = b0.z; acc[3] = b0.w;
        acc[4] = b1.x; acc[5] = b1.y; acc[6] = b1.z; acc[7] = b1.w;
    }
#pragma unroll
    for (int k = 0; k < 4; ++k) {
        if (l + k - 3 >= 0) {
            bf16x8 xv = *(const bf16x8*)&xzb[(size_t)(m + k - 3) * NXZ + e];
#pragma unroll
            for (int c = 0; c < 8; ++c)
                acc[c] = fmaf((float)xv[c], wv[c][k], acc[c]);
        }
    }
    bf16x8 o;
#pragma unroll
    for (int c = 0; c < 8; ++c)
        o[c] = (bf16)(acc[c] / (1.f + __expf(-acc[c])));
    *(bf16x8*)&u[(size_t)m * DI + e] = o;
}

// ============================================================================
// Chunked selective scan, NC=32 chunks of CL=64.  delta staged in LDS;
// u read per-step from global via 8-deep register prefetch ring (drops the
// 32 KiB sU tile -> 36/40 KiB LDS -> 4 blocks/CU, 2x the TLP).
// ============================================================================
__global__ __launch_bounds__(256, 4)
void scan_pass1(const bf16* __restrict__ xzb, const bf16* __restrict__ ub,
                const bf16* __restrict__ xdb, const float* __restrict__ A_log,
                float* __restrict__ Pend, float* __restrict__ Qend)
{
    __shared__ bf16 sD[CL][256];           // 32 KiB
    __shared__ float Bs[CL][DS];           // 4 KiB (36 KiB total -> 4 blk/CU)
    const int tid = threadIdx.x;
    const int e0 = blockIdx.x * 256;
    const int e  = e0 + tid;
    const int c = blockIdx.y;
    const int b = blockIdx.z;
    const int l0 = c * CL;

#pragma unroll
    for (int it = 0; it < CL / 8; ++it) {
        const int r   = it * 8 + (tid >> 5);
        const int col = (tid & 31) * 8;
        *(bf16x8*)&sD[r][col] = *(const bf16x8*)&xzb[(size_t)(b * L + l0 + r) * NXZ + e0 + col];
    }
#pragma unroll
    for (int it = 0; it < CL * DS / 256; ++it) {
        const int idx = it * 256 + tid;
        Bs[idx >> 4][idx & 15] =
            (float)xdb[(size_t)(b * L + l0 + (idx >> 4)) * NXD + DTR + (idx & 15)];
    }

    float A2[DS];
#pragma unroll
    for (int q = 0; q < 4; ++q) {
        float4 al = *(const float4*)(A_log + (size_t)e * DS + q * 4);
        A2[q * 4 + 0] = -__expf(al.x) * LOG2E;
        A2[q * 4 + 1] = -__expf(al.y) * LOG2E;
        A2[q * 4 + 2] = -__expf(al.z) * LOG2E;
        A2[q * 4 + 3] = -__expf(al.w) * LOG2E;
    }

    // 8-deep u prefetch ring (compile-time slot indices — no scratch)
    const size_t uidx = (size_t)(b * L + l0) * DI + e;
    bf16 ur[8];
#pragma unroll
    for (int j = 0; j < 8; ++j) ur[j] = ub[uidx + (size_t)j * DI];

    float h[DS];
#pragma unroll
    for (int n = 0; n < DS; ++n) h[n] = 0.f;
    float sumd = 0.f;

    __syncthreads();

    for (int t8 = 0; t8 < CL; t8 += 8) {
        const bool more = (t8 + 8 < CL);
#pragma unroll
        for (int j = 0; j < 8; ++j) {
            const int t = t8 + j;
            const float dv = (float)sD[t][tid];
            const float uv = (float)ur[j];
            const float du = dv * uv;
            sumd += dv;
#pragma unroll
            for (int n = 0; n < DS; ++n) {
                const float a = ex2(dv * A2[n]);
                h[n] = fmaf(a, h[n], du * Bs[t][n]);
            }
            if (more) ur[j] = ub[uidx + (size_t)(t + 8) * DI];
        }
    }

    const size_t o = ((size_t)(c * Bsz + b) * DI + e) * DS;
#pragma unroll
    for (int q = 0; q < 4; ++q) {
        f32x4 P = {ex2(A2[q*4] * sumd), ex2(A2[q*4+1] * sumd),
                   ex2(A2[q*4+2] * sumd), ex2(A2[q*4+3] * sumd)};
        *(f32x4*)(Pend + o + q * 4) = P;
        *(float4*)(Qend + o + q * 4) = make_float4(h[q*4], h[q*4+1], h[q*4+2], h[q*4+3]);
    }
}

__global__ __launch_bounds__(256)
void scan_pass2(const float* __restrict__ Pend, const float* __restrict__ Qend,
                float* __restrict__ H0)
{
    const int g = blockIdx.x * 256 + threadIdx.x;
    const int stride = Bsz * DI * DS;
    float P[NC], Q[NC];
#pragma unroll
    for (int c = 0; c < NC; ++c) {
        P[c] = Pend[(size_t)c * stride + g];
        Q[c] = Qend[(size_t)c * stride + g];
    }
    float h = 0.f;
#pragma unroll
    for (int c = 0; c < NC; ++c) {
        H0[(size_t)c * stride + g] = h;
        h = fmaf(P[c], h, Q[c]);
    }
}

__global__ __launch_bounds__(256, 4)
void scan_pass3(bf16* __restrict__ xzb, const bf16* __restrict__ ub,
                const bf16* __restrict__ xdb, const float* __restrict__ A_log,
                const float* __restrict__ Dp, const float* __restrict__ H0)
{
    __shared__ bf16 sD[CL][256];           // 32 KiB (delta in, ungated y out)
    __shared__ float BCs[CL][2 * DS];      // 8 KiB (40 KiB total -> 4 blk/CU)
    const int tid = threadIdx.x;
    const int e0 = blockIdx.x * 256;
    const int e  = e0 + tid;
    const int c = blockIdx.y;
    const int b = blockIdx.z;
    const int l0 = c * CL;

#pragma unroll
    for (int it = 0; it < CL / 8; ++it) {
        const int r   = it * 8 + (tid >> 5);
        const int col = (tid & 31) * 8;
        *(bf16x8*)&sD[r][col] = *(const bf16x8*)&xzb[(size_t)(b * L + l0 + r) * NXZ + e0 + col];
    }
#pragma unroll
    for (int it = 0; it < CL * 2 * DS / 256; ++it) {
        const int idx = it * 256 + tid;
        BCs[idx >> 5][idx & 31] =
            (float)xdb[(size_t)(b * L + l0 + (idx >> 5)) * NXD + DTR + (idx & 31)];
    }

    float A2[DS];
#pragma unroll
    for (int q = 0; q < 4; ++q) {
        float4 al = *(const float4*)(A_log + (size_t)e * DS + q * 4);
        A2[q * 4 + 0] = -__expf(al.x) * LOG2E;
        A2[q * 4 + 1] = -__expf(al.y) * LOG2E;
        A2[q * 4 + 2] = -__expf(al.z) * LOG2E;
        A2[q * 4 + 3] = -__expf(al.w) * LOG2E;
    }

    // 8-deep u prefetch ring
    const size_t uidx = (size_t)(b * L + l0) * DI + e;
    bf16 ur[8];
#pragma unroll
    for (int j = 0; j < 8; ++j) ur[j] = ub[uidx + (size_t)j * DI];

    float h[DS];
    const size_t o = (size_t)c * (Bsz * DI * DS) + ((size_t)b * DI + e) * DS;
#pragma unroll
    for (int q = 0; q < 4; ++q) {
        float4 hv = *(const float4*)(H0 + o + q * 4);
        h[q*4] = hv.x; h[q*4+1] = hv.y; h[q*4+2] = hv.z; h[q*4+3] = hv.w;
    }
    const float Dval = Dp[e];

    __syncthreads();

    for (int t8 = 0; t8 < CL; t8 += 8) {
        const bool more = (t8 + 8 < CL);
#pragma unroll
        for (int j = 0; j < 8; ++j) {
            const int t = t8 + j;
            const float dv = (float)sD[t][tid];
            const float uv = (float)ur[j];
            const float du = dv * uv;
            float y = 0.f;
#pragma unroll
            for (int n = 0; n < DS; ++n) {
                const float a = ex2(dv * A2[n]);
                h[n] = fmaf(a, h[n], du * BCs[t][n]);
                y = fmaf(h[n], BCs[t][DS + n], y);
            }
            sD[t][tid] = (bf16)(y + uv * Dval);    // ungated y over delta tile
            if (more) ur[j] = ub[uidx + (size_t)(t + 8) * DI];
        }
    }

    __syncthreads();
    // gated writeback (coalesced global z read)
#pragma unroll
    for (int it = 0; it < CL / 8; ++it) {
        const int r   = it * 8 + (tid >> 5);
        const int col = (tid & 31) * 8;
        const size_t grow = (size_t)(b * L + l0 + r);
        bf16x8 zv = *(const bf16x8*)&xzb[grow * NXZ + DI + e0 + col];
        bf16x8 yv = *(bf16x8*)&sD[r][col];
        bf16x8 ov;
#pragma unroll
        for (int j = 0; j < 8; ++j) {
            const float z = (float)zv[j];
            ov[j] = (bf16)((float)yv[j] * (z / (1.f + __expf(-z))));
        }
        *(bf16x8*)&xzb[grow * NXZ + e0 + col] = ov;
    }
}

// ============================================================================
extern "C" void kernel_launch(void* const* d_in, const int* in_sizes, int n_in,
                              void* d_out, int out_size, void* d_ws, size_t ws_size,
                              hipStream_t stream)
{
    const float* x          = (const float*)d_in[0];
    const float* in_proj_w  = (const float*)d_in[1];
    const float* conv_w     = (const float*)d_in[2];
    const float* conv_b     = (const float*)d_in[3];
    const float* x_proj_w   = (const float*)d_in[4];
    const float* dt_proj_w  = (const float*)d_in[5];
    const float* dt_proj_b  = (const float*)d_in[6];
    const float* A_log      = (const float*)d_in[7];
    const float* Dp         = (const float*)d_in[8];
    const float* out_proj_w = (const float*)d_in[9];
    float* out = (float*)d_out;

    bf16* xzb   = (bf16*)d_ws;
    bf16* ub    = xzb   + (size_t)M * NXZ;
    bf16* xdb   = ub    + (size_t)M * DI;
    bf16* xb    = xdb   + (size_t)M * NXD;
    bf16* wbin  = xb    + (size_t)M * DM;
    bf16* wbout = wbin  + (size_t)NXZ * DM;
    bf16* wbxp  = wbout + (size_t)DM * DI;
    bf16* wbdt  = wbxp  + (size_t)NXD * DI;
    float* Pend = (float*)(wbdt + (size_t)DI * DTR);
    float* Qend = Pend + (size_t)NC * Bsz * DI * DS;
    float* H0   = Qend + (size_t)NC * Bsz * DI * DS;
    float* xpart = Pend;

    const dim3 blk(256);

    // 0. fused cast of all inputs/weights to bf16
    cast_all<<<dim3(C4 / 256), blk, 0, stream>>>(
        x, in_proj_w, out_proj_w, x_proj_w, dt_proj_w,
        xb, wbin, wbout, wbxp, wbdt);

    // 1. in_proj: xz = x @ in_proj_w^T  [4096, 4096] — 256² 8-phase kernel
    gemm256_inproj<<<dim3(256), dim3(512), 0, stream>>>(xb, wbin, xzb);

    // 2. causal conv + SiLU -> u bf16
    conv_silu<<<dim3(M * (DI / 8) / 256), blk, 0, stream>>>(xzb, conv_w, conv_b, ub);

    // 3. x_dbl = u @ x_proj_w^T  via split-K + reduce
    gemm_xproj<<<dim3(M / 128, KS), blk, 0, stream>>>(ub, wbxp, xpart);
    reduce_xdbl<<<dim3(M * 96 / 256), blk, 0, stream>>>(xpart, xdb);

    // 4. delta = softplus(x_dbl[:,:64] @ dt_proj_w^T + b) -> xzb cols [0,DI)
    gemm_bf16<1><<<dim3(DI / 128, M / 128), blk, 0, stream>>>(
        xdb, wbdt, dt_proj_b, nullptr, xzb, DI, DTR, NXD, NXZ);

    // 5. chunked selective scan; y (bf16) overwrites delta in xzb
    scan_pass1<<<dim3(DI / 256, NC, Bsz), blk, 0, stream>>>(xzb, ub, xdb, A_log, Pend, Qend);
    scan_pass2<<<dim3(Bsz * DI * DS / 256), blk, 0, stream>>>(Pend, Qend, H0);
    scan_pass3<<<dim3(DI / 256, NC, Bsz), blk, 0, stream>>>(xzb, ub, xdb, A_log, Dp, H0);

    // 6. out = x + y @ out_proj_w^T  [4096, 1024] fp32 — 4-deep ring
    gemm_out<<<dim3(512), blk, 0, stream>>>(xzb, wbout, x, out);
}

// Round 17
// 243.866 us; speedup vs baseline: 1.0168x; 1.0168x over previous
//
#include <hip/hip_runtime.h>
#include <hip/hip_bf16.h>
#include <math.h>

typedef __bf16 bf16;
typedef __attribute__((ext_vector_type(8))) __bf16 bf16x8;
typedef __attribute__((ext_vector_type(4))) __bf16 bf16x4;
typedef __attribute__((ext_vector_type(4))) float  f32x4;

// ---- problem dims (fixed by reference) ----
static constexpr int Bsz = 2, L = 2048, DM = 1024, DI = 2048, DS = 16, DTR = 64;
static constexpr int M   = Bsz * L;        // 4096 tokens
static constexpr int NXZ = 2 * DI;         // 4096
static constexpr int NXD = DTR + 2 * DS;   // 96
static constexpr int NC  = 32;             // scan chunks
static constexpr int CL  = L / NC;         // 64 steps per chunk
static constexpr int KS  = 8;              // x_proj K-splits
static constexpr float LOG2E = 1.4426950408889634f;

// raw v_exp_f32 (trans pipe), no OCML wrapper
__device__ inline float ex2(float x) { return __builtin_amdgcn_exp2f(x); }

__device__ inline void gload_lds16(const void* g, void* l)
{
    __builtin_amdgcn_global_load_lds(
        (const __attribute__((address_space(1))) void*)g,
        (__attribute__((address_space(3))) void*)l, 16, 0, 0);
}

#define SBAR() { asm volatile("" ::: "memory"); __builtin_amdgcn_s_barrier(); asm volatile("" ::: "memory"); }
#define VMCNT12() asm volatile("s_waitcnt vmcnt(12)" ::: "memory")
#define VMCNT9()  asm volatile("s_waitcnt vmcnt(9)" ::: "memory")
#define VMCNT8()  asm volatile("s_waitcnt vmcnt(8)" ::: "memory")
#define VMCNT6()  asm volatile("s_waitcnt vmcnt(6)" ::: "memory")
#define VMCNT4()  asm volatile("s_waitcnt vmcnt(4)" ::: "memory")
#define VMCNT3()  asm volatile("s_waitcnt vmcnt(3)" ::: "memory")
#define VMCNT0()  asm volatile("s_waitcnt vmcnt(0)" ::: "memory")

// Additive LDS k-slot swizzle (conflict-free in every 8-lane read group):
//  stage source slot for thread: ((tid&3) - ((tid>>3)&3)) & 3
//  read position for (ko16, fr): (ko16 + ((fr>>1)&3)) & 3

// ============================================================================
// Fused fp32 -> bf16 cast of all 5 tensors (one launch, float4 granularity).
// ============================================================================
static constexpr int C0 = M * DM / 4;            // x
static constexpr int C1 = C0 + NXZ * DM / 4;     // in_w
static constexpr int C2 = C1 + DM * DI / 4;      // out_w
static constexpr int C3 = C2 + NXD * DI / 4;     // xp_w
static constexpr int C4 = C3 + DI * DTR / 4;     // dt_w

__global__ __launch_bounds__(256)
void cast_all(const float* __restrict__ s0, const float* __restrict__ s1,
              const float* __restrict__ s2, const float* __restrict__ s3,
              const float* __restrict__ s4,
              bf16* __restrict__ d0, bf16* __restrict__ d1,
              bf16* __restrict__ d2, bf16* __restrict__ d3,
              bf16* __restrict__ d4)
{
    const int i = blockIdx.x * 256 + threadIdx.x;
    const float* s; bf16* d; int off;
    if      (i < C0) { s = s0; d = d0; off = 0;  }
    else if (i < C1) { s = s1; d = d1; off = C0; }
    else if (i < C2) { s = s2; d = d2; off = C1; }
    else if (i < C3) { s = s3; d = d3; off = C2; }
    else             { s = s4; d = d4; off = C3; }
    const int j = i - off;
    float4 v = ((const float4*)s)[j];
    bf16x4 o = {(bf16)v.x, (bf16)v.y, (bf16)v.z, (bf16)v.w};
    ((bf16x4*)d)[j] = o;
}

// ============================================================================
// 256x256 8-phase bf16 MFMA GEMM for in_proj (M=4096, N=4096, K=1024).
// ============================================================================
static constexpr int GK  = DM;        // 1024
static constexpr int GNT = GK / 64;   // 16 K-tiles

__device__ __forceinline__ void stage_half(const bf16* __restrict__ Gbase, int ld,
                                           int kbase, bf16* lds_slot, int tid, int wid)
{
    const int rl = tid >> 2;                                      // 0..127
    const int ks = ((((tid & 3) - ((tid >> 3) & 3)) & 3) << 3);   // additive swizzle src
#pragma unroll
    for (int i = 0; i < 2; ++i)
        gload_lds16(Gbase + (size_t)(i * 128 + rl) * ld + kbase + ks,
                    lds_slot + i * 4096 + wid * 512);
}

template<int MH>
__device__ __forceinline__ void ldA4(const bf16* As, int abase, bf16x8 af[4])
{
#pragma unroll
    for (int mm = 0; mm < 4; ++mm)
        af[mm] = *(const bf16x8*)(As + abase + (MH * 4 + mm) * 512);
}

__device__ __forceinline__ void ldB4(const bf16* Bs, int bbase, bf16x8 bfr[4])
{
#pragma unroll
    for (int nn = 0; nn < 4; ++nn)
        bfr[nn] = *(const bf16x8*)(Bs + bbase + nn * 512);
}

template<int MH>
__device__ __forceinline__ void mfma16(f32x4 acc[8][4], const bf16x8 af[4],
                                       const bf16x8 bfr[4])
{
#pragma unroll
    for (int mm = 0; mm < 4; ++mm)
#pragma unroll
        for (int nn = 0; nn < 4; ++nn)
            acc[MH * 4 + mm][nn] = __builtin_amdgcn_mfma_f32_16x16x32_bf16(
                af[mm], bfr[nn], acc[MH * 4 + mm][nn], 0, 0, 0);
}

__global__ __launch_bounds__(512, 1)
void gemm256_inproj(const bf16* __restrict__ A, const bf16* __restrict__ Bw,
                    bf16* __restrict__ C)
{
    __shared__ __align__(16) bf16 Asl[4 * 8192];   // 64 KiB (4 slots [256][32])
    __shared__ __align__(16) bf16 Bsl[4 * 8192];   // 64 KiB

    const int tid  = threadIdx.x;
    const int wid  = tid >> 6;
    const int lane = tid & 63;
    const int wr   = wid >> 2;            // 0..1
    const int wc   = wid & 3;             // 0..3
    const int fr   = lane & 15;
    const int ko16 = lane >> 4;           // 0..3 (k 16B slot wanted)
    const int kx   = (((ko16 + ((fr >> 1) & 3)) & 3) << 3);   // swizzled read pos

    // XCD-aware bijective swizzle (256 blocks, 8 XCDs)
    const int bid = blockIdx.x;
    const int wg  = (bid & 7) * 32 + (bid >> 3);
    const int by  = wg >> 4, bx = wg & 15;
    const int row0 = by * 256, col0 = bx * 256;

    const bf16* Ablk = A  + (size_t)row0 * GK;
    const bf16* Bblk = Bw + (size_t)col0 * GK;

    const int abase = (wr * 128 + fr) * 32 + kx;
    const int bbase = (wc * 64 + fr) * 32 + kx;

    f32x4 acc[8][4] = {};
    bf16x8 af[4], bfr[4];

    // ---- prologue: stage t0 (h0,h1) + t1 (h0) = 12 gloads ----
    stage_half(Ablk, GK, 0,       Asl + 0 * 8192, tid, wid);   // t0 h0 -> slot0
    stage_half(Bblk, GK, 0,       Bsl + 0 * 8192, tid, wid);
    stage_half(Ablk, GK, 32,      Asl + 1 * 8192, tid, wid);   // t0 h1 -> slot1
    stage_half(Bblk, GK, 32,      Bsl + 1 * 8192, tid, wid);
    stage_half(Ablk, GK, 64,      Asl + 2 * 8192, tid, wid);   // t1 h0 -> slot2
    stage_half(Bblk, GK, 64,      Bsl + 2 * 8192, tid, wid);
    VMCNT4();          // t0 fully landed; t1-h0 (4 loads) in flight
    SBAR();

    for (int t = 0; t < GNT; ++t) {
        const int sk0 = (2 * t) & 3, sk1 = (2 * t + 1) & 3;
        const bf16* As0 = Asl + sk0 * 8192;
        const bf16* As1 = Asl + sk1 * 8192;
        const bf16* Bs0 = Bsl + sk0 * 8192;
        const bf16* Bs1 = Bsl + sk1 * 8192;

        // ---- phase 0: mh=0, ks=0 ----
        ldA4<0>(As0, abase, af);
        ldB4(Bs0, bbase, bfr);
        if (t + 1 < GNT)
            stage_half(Ablk, GK, (t + 1) * 64 + 32, Asl + ((2 * t + 3) & 3) * 8192, tid, wid);
        SBAR();
        __builtin_amdgcn_s_setprio(1);
        mfma16<0>(acc, af, bfr);
        __builtin_amdgcn_s_setprio(0);
        SBAR();

        // ---- phase 1: mh=1, ks=0 (B reuse) ----
        ldA4<1>(As0, abase, af);
        if (t + 1 < GNT)
            stage_half(Bblk, GK, (t + 1) * 64 + 32, Bsl + ((2 * t + 3) & 3) * 8192, tid, wid);
        SBAR();
        __builtin_amdgcn_s_setprio(1);
        mfma16<1>(acc, af, bfr);
        __builtin_amdgcn_s_setprio(0);
        SBAR();

        // ---- phase 2: mh=0, ks=1 ----
        ldA4<0>(As1, abase, af);
        ldB4(Bs1, bbase, bfr);
        if (t + 2 < GNT)
            stage_half(Ablk, GK, (t + 2) * 64, Asl + sk0 * 8192, tid, wid);
        SBAR();
        __builtin_amdgcn_s_setprio(1);
        mfma16<0>(acc, af, bfr);
        __builtin_amdgcn_s_setprio(0);
        SBAR();

        // ---- phase 3: mh=1, ks=1 (B reuse) ----
        ldA4<1>(As1, abase, af);
        if (t + 2 < GNT)
            stage_half(Bblk, GK, (t + 2) * 64, Bsl + sk0 * 8192, tid, wid);
        SBAR();
        __builtin_amdgcn_s_setprio(1);
        mfma16<1>(acc, af, bfr);
        __builtin_amdgcn_s_setprio(0);
        if (t < GNT - 3) { VMCNT4(); } else { VMCNT0(); }
        SBAR();
    }

    // ---- epilogue: C/D layout col=lane&15, row=(lane>>4)*4+reg ----
    const int r0 = row0 + wr * 128 + (ko16 << 2);
    const int c0 = col0 + wc * 64 + fr;
#pragma unroll
    for (int m = 0; m < 8; ++m)
#pragma unroll
        for (int n = 0; n < 4; ++n)
#pragma unroll
            for (int r = 0; r < 4; ++r)
                C[(size_t)(r0 + m * 16 + r) * NXZ + c0 + n * 16] = (bf16)acc[m][n][r];
}

// ============================================================================
// out_proj GEMM: out[M,1024] = y[M,2048] @ Wout[1024,2048]^T + x  (fp32 out).
// BM=128, BN=64, 512 blocks (2/CU), bijective XCD swizzle.
// 4-slot LDS ring, 3-deep prefetch, counted vmcnt(9/6/3/0).
// ============================================================================
__global__ __launch_bounds__(256)
void gemm_out(const bf16* __restrict__ A, const bf16* __restrict__ Bw,
              const float* __restrict__ res, float* __restrict__ Cout)
{
    __shared__ __align__(16) bf16 Asl[4][128 * 32];   // 4 x 8 KiB
    __shared__ __align__(16) bf16 Bsl[4][64 * 32];    // 4 x 4 KiB  (48 KiB total)

    const int tid  = threadIdx.x;
    const int bid  = blockIdx.x;
    const int orig = (bid & 7) * 64 + (bid >> 3);
    const int bx   = orig & 15;           // col block 0..15
    const int by   = orig >> 4;           // row block 0..31
    const int row0 = by * 128, col0 = bx * 64;

    const int w    = tid >> 6;
    const int lane = tid & 63;
    const int wr   = w >> 1, wc = w & 1;
    const int fr   = lane & 15;
    const int ko   = (((lane >> 4) + ((fr >> 1) & 3)) & 3) << 3;  // swizzled read

    f32x4 acc[4][2] = {};

    const int sr  = tid >> 2;             // 0..63
    const int ssk = ((((tid & 3) - ((tid >> 3) & 3)) & 3) << 3);  // swizzled src
    const bf16* gA0 = A  + (size_t)(row0 + sr) * NXZ + ssk;
    const bf16* gA1 = A  + (size_t)(row0 + 64 + sr) * NXZ + ssk;
    const bf16* gB0 = Bw + (size_t)(col0 + sr) * DI + ssk;

    const int NT = DI / 32;               // 64 K-iterations

#define STAGE_OUT(s, kk) do { \
        gload_lds16(gA0 + (kk), (char*)Asl[s] + w * 1024); \
        gload_lds16(gA1 + (kk), (char*)Asl[s] + 4096 + w * 1024); \
        gload_lds16(gB0 + (kk), (char*)Bsl[s] + w * 1024); } while (0)

    STAGE_OUT(0, 0);
    STAGE_OUT(1, 32);
    STAGE_OUT(2, 64);
    for (int i = 0; i < NT; ++i) {
        const int cur = i & 3;
        if (i + 3 < NT)      { STAGE_OUT((i + 3) & 3, (i + 3) * 32); VMCNT9(); }
        else if (i + 2 < NT) { VMCNT6(); }
        else if (i + 1 < NT) { VMCNT3(); }
        else                 { VMCNT0(); }
        SBAR();

        bf16x8 af[4], bfr[2];
#pragma unroll
        for (int m = 0; m < 4; ++m)
            af[m] = *(const bf16x8*)&Asl[cur][((wr << 6) + m * 16 + fr) * 32 + ko];
#pragma unroll
        for (int n = 0; n < 2; ++n)
            bfr[n] = *(const bf16x8*)&Bsl[cur][((wc << 5) + n * 16 + fr) * 32 + ko];
        __builtin_amdgcn_s_setprio(1);
#pragma unroll
        for (int m = 0; m < 4; ++m)
#pragma unroll
            for (int n = 0; n < 2; ++n)
                acc[m][n] = __builtin_amdgcn_mfma_f32_16x16x32_bf16(
                    af[m], bfr[n], acc[m][n], 0, 0, 0);
        __builtin_amdgcn_s_setprio(0);
        SBAR();
    }
#undef STAGE_OUT

    const int r0 = row0 + (wr << 6) + ((lane >> 4) << 2);
    const int c0 = col0 + (wc << 5) + fr;
#pragma unroll
    for (int m = 0; m < 4; ++m)
#pragma unroll
        for (int n = 0; n < 2; ++n)
#pragma unroll
            for (int r = 0; r < 4; ++r) {
                const int row = r0 + m * 16 + r;
                const int col = c0 + n * 16;
                Cout[(size_t)row * DM + col] =
                    acc[m][n][r] + res[(size_t)row * DM + col];
            }
}

// ============================================================================
// bf16 MFMA TN GEMM (128x128, 2-phase) — used for dt_proj (K=64, 2 iters).
// ============================================================================
template<int EPI>
__global__ __launch_bounds__(256)
void gemm_bf16(const bf16* __restrict__ A, const bf16* __restrict__ Bw,
               const float* __restrict__ bias, const float* __restrict__ res,
               void* __restrict__ Cout, int N, int K, int lda, int ldc)
{
    __shared__ __align__(16) bf16 Asl[128 * 32];
    __shared__ __align__(16) bf16 Bsl[128 * 32];

    const int tid  = threadIdx.x;
    const int row0 = blockIdx.y * 128;
    const int col0 = blockIdx.x * 128;
    const int w    = tid >> 6;
    const int lane = tid & 63;
    const int wr   = w >> 1, wc = w & 1;
    const int fr   = lane & 15;
    const int ko   = (((lane >> 4) + ((fr >> 1) & 3)) & 3) << 3;

    f32x4 acc[4][4] = {};

    const int sr  = tid >> 2;
    const int ssk = ((((tid & 3) - ((tid >> 3) & 3)) & 3) << 3);
    int brow0 = col0 + sr;       if (brow0 > N - 1) brow0 = N - 1;
    int brow1 = col0 + 64 + sr;  if (brow1 > N - 1) brow1 = N - 1;
    const bf16* gA0 = A  + (size_t)(row0 + sr) * lda + ssk;
    const bf16* gA1 = A  + (size_t)(row0 + 64 + sr) * lda + ssk;
    const bf16* gB0 = Bw + (size_t)brow0 * K + ssk;
    const bf16* gB1 = Bw + (size_t)brow1 * K + ssk;
    char* lA = (char*)Asl + w * 1024;
    char* lB = (char*)Bsl + w * 1024;

    for (int k0 = 0; k0 < K; k0 += 32) {
        gload_lds16(gA0 + k0, lA);
        gload_lds16(gA1 + k0, lA + 4096);
        gload_lds16(gB0 + k0, lB);
        gload_lds16(gB1 + k0, lB + 4096);
        __syncthreads();

        bf16x8 af[4], bfr[4];
#pragma unroll
        for (int m = 0; m < 4; ++m)
            af[m] = *(const bf16x8*)&Asl[((wr << 6) + m * 16 + fr) * 32 + ko];
#pragma unroll
        for (int n = 0; n < 4; ++n)
            bfr[n] = *(const bf16x8*)&Bsl[((wc << 6) + n * 16 + fr) * 32 + ko];
#pragma unroll
        for (int m = 0; m < 4; ++m)
#pragma unroll
            for (int n = 0; n < 4; ++n)
                acc[m][n] = __builtin_amdgcn_mfma_f32_16x16x32_bf16(
                    af[m], bfr[n], acc[m][n], 0, 0, 0);
        __syncthreads();
    }

    const int r0 = row0 + (wr << 6) + ((lane >> 4) << 2);
    const int c0 = col0 + (wc << 6) + fr;
#pragma unroll
    for (int m = 0; m < 4; ++m) {
#pragma unroll
        for (int n = 0; n < 4; ++n) {
            const int col = c0 + n * 16;
            if (col < N) {
#pragma unroll
                for (int r = 0; r < 4; ++r) {
                    const int row = r0 + m * 16 + r;
                    float v = acc[m][n][r];
                    if (EPI == 1) {
                        v += bias[col];
                        v = (v > 20.f) ? v : log1pf(expf(v));
                        ((bf16*)Cout)[(size_t)row * ldc + col] = (bf16)v;
                    } else {
                        ((bf16*)Cout)[(size_t)row * ldc + col] = (bf16)v;
                    }
                }
            }
        }
    }
}

// ============================================================================
// x_proj split-K GEMM: 4-slot ring, 3-deep prefetch, vmcnt(12/8/4/0).
// ============================================================================
__global__ __launch_bounds__(256)
void gemm_xproj(const bf16* __restrict__ A, const bf16* __restrict__ Bw,
                float* __restrict__ Cpart)
{
    __shared__ __align__(16) bf16 Asl[4][128 * 32];   // 32 KiB
    __shared__ __align__(16) bf16 Bsl[4][128 * 32];   // 32 KiB

    const int tid  = threadIdx.x;
    const int row0 = blockIdx.x * 128;
    const int kz   = blockIdx.y;
    const int kb   = kz * (2048 / KS);
    const int w    = tid >> 6;
    const int lane = tid & 63;
    const int wr   = w >> 1, wc = w & 1;
    const int fr   = lane & 15;
    const int ko   = (((lane >> 4) + ((fr >> 1) & 3)) & 3) << 3;

    f32x4 acc[4][4] = {};

    const int sr  = tid >> 2;
    const int ssk = ((((tid & 3) - ((tid >> 3) & 3)) & 3) << 3);
    int brow0 = sr;       if (brow0 > 95) brow0 = 95;
    int brow1 = 64 + sr;  if (brow1 > 95) brow1 = 95;
    const bf16* gA0 = A  + (size_t)(row0 + sr) * DI + kb + ssk;
    const bf16* gA1 = A  + (size_t)(row0 + 64 + sr) * DI + kb + ssk;
    const bf16* gB0 = Bw + (size_t)brow0 * DI + kb + ssk;
    const bf16* gB1 = Bw + (size_t)brow1 * DI + kb + ssk;

    const int NT = (2048 / KS) / 32;      // 8 K-iterations

#define STAGE_XP(s, kk) do { \
        gload_lds16(gA0 + (kk), (char*)Asl[s] + w * 1024); \
        gload_lds16(gA1 + (kk), (char*)Asl[s] + 4096 + w * 1024); \
        gload_lds16(gB0 + (kk), (char*)Bsl[s] + w * 1024); \
        gload_lds16(gB1 + (kk), (char*)Bsl[s] + 4096 + w * 1024); } while (0)

    STAGE_XP(0, 0);
    STAGE_XP(1, 32);
    STAGE_XP(2, 64);
    for (int i = 0; i < NT; ++i) {
        const int cur = i & 3;
        if (i + 3 < NT)      { STAGE_XP((i + 3) & 3, (i + 3) * 32); VMCNT12(); }
        else if (i + 2 < NT) { VMCNT8(); }
        else if (i + 1 < NT) { VMCNT4(); }
        else                 { VMCNT0(); }
        SBAR();

        bf16x8 af[4], bfr[4];
#pragma unroll
        for (int m = 0; m < 4; ++m)
            af[m] = *(const bf16x8*)&Asl[cur][((wr << 6) + m * 16 + fr) * 32 + ko];
#pragma unroll
        for (int n = 0; n < 4; ++n)
            bfr[n] = *(const bf16x8*)&Bsl[cur][((wc << 6) + n * 16 + fr) * 32 + ko];
        __builtin_amdgcn_s_setprio(1);
#pragma unroll
        for (int m = 0; m < 4; ++m)
#pragma unroll
            for (int n = 0; n < 4; ++n)
                acc[m][n] = __builtin_amdgcn_mfma_f32_16x16x32_bf16(
                    af[m], bfr[n], acc[m][n], 0, 0, 0);
        __builtin_amdgcn_s_setprio(0);
        SBAR();
    }
#undef STAGE_XP

    const int r0 = (wr << 6) + ((lane >> 4) << 2);
    const int c0 = (wc << 6) + fr;
    float* Cp = Cpart + (size_t)kz * M * 96 + (size_t)row0 * 96;
#pragma unroll
    for (int m = 0; m < 4; ++m) {
#pragma unroll
        for (int n = 0; n < 4; ++n) {
            const int col = c0 + n * 16;
            if (col < 96) {
#pragma unroll
                for (int r = 0; r < 4; ++r)
                    Cp[(size_t)(r0 + m * 16 + r) * 96 + col] = acc[m][n][r];
            }
        }
    }
}

__global__ __launch_bounds__(256)
void reduce_xdbl(const float* __restrict__ part, bf16* __restrict__ xdb)
{
    const int i = blockIdx.x * 256 + threadIdx.x;
    if (i >= M * 96) return;
    float s = 0.f;
#pragma unroll
    for (int k = 0; k < KS; ++k) s += part[(size_t)k * M * 96 + i];
    xdb[i] = (bf16)s;
}

// ============================================================================
// Causal depthwise conv1d (d_conv=4) + bias + SiLU.
// ============================================================================
__global__ __launch_bounds__(256)
void conv_silu(const bf16* __restrict__ xzb, const float* __restrict__ cw,
               const float* __restrict__ cb, bf16* __restrict__ u)
{
    const int idx = blockIdx.x * 256 + threadIdx.x;
    const int e   = (idx & 255) * 8;
    const int m   = idx >> 8;
    const int l   = m & (L - 1);

    float wv[8][4];
#pragma unroll
    for (int c = 0; c < 8; ++c) {
        float4 t = *(const float4*)(cw + (size_t)(e + c) * 4);
        wv[c][0] = t.x; wv[c][1] = t.y; wv[c][2] = t.z; wv[c][3] = t.w;
    }
    float acc[8];
    {
        float4 b0 = *(const float4*)(cb + e);
        float4 b1 = *(const float4*)(cb + e + 4);
        acc[0] = b0.x; acc[1] = b0.y; acc[2] = b0.z; acc[3] = b0.w;
        acc[4] = b1.x; acc[5] = b1.y; acc[6] = b1.z; acc[7] = b1.w;
    }
#pragma unroll
    for (int k = 0; k < 4; ++k) {
        if (l + k - 3 >= 0) {
            bf16x8 xv = *(const bf16x8*)&xzb[(size_t)(m + k - 3) * NXZ + e];
#pragma unroll
            for (int c = 0; c < 8; ++c)
                acc[c] = fmaf((float)xv[c], wv[c][k], acc[c]);
        }
    }
    bf16x8 o;
#pragma unroll
    for (int c = 0; c < 8; ++c)
        o[c] = (bf16)(acc[c] / (1.f + __expf(-acc[c])));
    *(bf16x8*)&u[(size_t)m * DI + e] = o;
}

// ============================================================================
// Chunked selective scan, LDS-staged, native v_exp.  NC=32 chunks of CL=64.
// ============================================================================
__global__ __launch_bounds__(256)
void scan_pass1(const bf16* __restrict__ xzb, const bf16* __restrict__ ub,
                const bf16* __restrict__ xdb, const float* __restrict__ A_log,
                float* __restrict__ Pend, float* __restrict__ Qend)
{
    __shared__ bf16 sD[CL][256];
    __shared__ bf16 sU[CL][256];
    __shared__ float Bs[CL][DS];
    const int tid = threadIdx.x;
    const int e0 = blockIdx.x * 256;
    const int e  = e0 + tid;
    const int c = blockIdx.y;
    const int b = blockIdx.z;
    const int l0 = c * CL;

#pragma unroll
    for (int it = 0; it < CL / 8; ++it) {
        const int r   = it * 8 + (tid >> 5);
        const int col = (tid & 31) * 8;
        *(bf16x8*)&sD[r][col] = *(const bf16x8*)&xzb[(size_t)(b * L + l0 + r) * NXZ + e0 + col];
        *(bf16x8*)&sU[r][col] = *(const bf16x8*)&ub [(size_t)(b * L + l0 + r) * DI  + e0 + col];
    }
#pragma unroll
    for (int it = 0; it < CL * DS / 256; ++it) {
        const int idx = it * 256 + tid;
        Bs[idx >> 4][idx & 15] =
            (float)xdb[(size_t)(b * L + l0 + (idx >> 4)) * NXD + DTR + (idx & 15)];
    }

    float A2[DS];
#pragma unroll
    for (int q = 0; q < 4; ++q) {
        float4 al = *(const float4*)(A_log + (size_t)e * DS + q * 4);
        A2[q * 4 + 0] = -__expf(al.x) * LOG2E;
        A2[q * 4 + 1] = -__expf(al.y) * LOG2E;
        A2[q * 4 + 2] = -__expf(al.z) * LOG2E;
        A2[q * 4 + 3] = -__expf(al.w) * LOG2E;
    }

    float h[DS];
#pragma unroll
    for (int n = 0; n < DS; ++n) h[n] = 0.f;
    float sumd = 0.f;

    __syncthreads();

#pragma unroll 4
    for (int t = 0; t < CL; ++t) {
        const float dv = (float)sD[t][tid];
        const float uv = (float)sU[t][tid];
        const float du = dv * uv;
        sumd += dv;
#pragma unroll
        for (int n = 0; n < DS; ++n) {
            const float a = ex2(dv * A2[n]);
            h[n] = fmaf(a, h[n], du * Bs[t][n]);
        }
    }

    const size_t o = ((size_t)(c * Bsz + b) * DI + e) * DS;
#pragma unroll
    for (int q = 0; q < 4; ++q) {
        f32x4 P = {ex2(A2[q*4] * sumd), ex2(A2[q*4+1] * sumd),
                   ex2(A2[q*4+2] * sumd), ex2(A2[q*4+3] * sumd)};
        *(f32x4*)(Pend + o + q * 4) = P;
        *(float4*)(Qend + o + q * 4) = make_float4(h[q*4], h[q*4+1], h[q*4+2], h[q*4+3]);
    }
}

__global__ __launch_bounds__(256)
void scan_pass2(const float* __restrict__ Pend, const float* __restrict__ Qend,
                float* __restrict__ H0)
{
    const int g = blockIdx.x * 256 + threadIdx.x;
    const int stride = Bsz * DI * DS;
    float P[NC], Q[NC];
#pragma unroll
    for (int c = 0; c < NC; ++c) {
        P[c] = Pend[(size_t)c * stride + g];
        Q[c] = Qend[(size_t)c * stride + g];
    }
    float h = 0.f;
#pragma unroll
    for (int c = 0; c < NC; ++c) {
        H0[(size_t)c * stride + g] = h;
        h = fmaf(P[c], h, Q[c]);
    }
}

__global__ __launch_bounds__(256)
void scan_pass3(bf16* __restrict__ xzb, const bf16* __restrict__ ub,
                const bf16* __restrict__ xdb, const float* __restrict__ A_log,
                const float* __restrict__ Dp, const float* __restrict__ H0)
{
    __shared__ bf16 sD[CL][256];
    __shared__ bf16 sU[CL][256];
    __shared__ float BCs[CL][2 * DS];
    const int tid = threadIdx.x;
    const int e0 = blockIdx.x * 256;
    const int e  = e0 + tid;
    const int c = blockIdx.y;
    const int b = blockIdx.z;
    const int l0 = c * CL;

#pragma unroll
    for (int it = 0; it < CL / 8; ++it) {
        const int r   = it * 8 + (tid >> 5);
        const int col = (tid & 31) * 8;
        const size_t grow = (size_t)(b * L + l0 + r);
        *(bf16x8*)&sD[r][col] = *(const bf16x8*)&xzb[grow * NXZ + e0 + col];
        *(bf16x8*)&sU[r][col] = *(const bf16x8*)&ub [grow * DI + e0 + col];
    }
#pragma unroll
    for (int it = 0; it < CL * 2 * DS / 256; ++it) {
        const int idx = it * 256 + tid;
        BCs[idx >> 5][idx & 31] =
            (float)xdb[(size_t)(b * L + l0 + (idx >> 5)) * NXD + DTR + (idx & 31)];
    }

    float A2[DS];
#pragma unroll
    for (int q = 0; q < 4; ++q) {
        float4 al = *(const float4*)(A_log + (size_t)e * DS + q * 4);
        A2[q * 4 + 0] = -__expf(al.x) * LOG2E;
        A2[q * 4 + 1] = -__expf(al.y) * LOG2E;
        A2[q * 4 + 2] = -__expf(al.z) * LOG2E;
        A2[q * 4 + 3] = -__expf(al.w) * LOG2E;
    }

    float h[DS];
    const size_t o = (size_t)c * (Bsz * DI * DS) + ((size_t)b * DI + e) * DS;
#pragma unroll
    for (int q = 0; q < 4; ++q) {
        float4 hv = *(const float4*)(H0 + o + q * 4);
        h[q*4] = hv.x; h[q*4+1] = hv.y; h[q*4+2] = hv.z; h[q*4+3] = hv.w;
    }
    const float Dval = Dp[e];

    __syncthreads();

#pragma unroll 4
    for (int t = 0; t < CL; ++t) {
        const float dv = (float)sD[t][tid];
        const float uv = (float)sU[t][tid];
        const float du = dv * uv;
        float y = 0.f;
#pragma unroll
        for (int n = 0; n < DS; ++n) {
            const float a = ex2(dv * A2[n]);
            h[n] = fmaf(a, h[n], du * BCs[t][n]);
            y = fmaf(h[n], BCs[t][DS + n], y);
        }
        sD[t][tid] = (bf16)(y + uv * Dval);
    }

    __syncthreads();
#pragma unroll
    for (int it = 0; it < CL / 8; ++it) {
        const int r   = it * 8 + (tid >> 5);
        const int col = (tid & 31) * 8;
        const size_t grow = (size_t)(b * L + l0 + r);
        bf16x8 zv = *(const bf16x8*)&xzb[grow * NXZ + DI + e0 + col];
        bf16x8 yv = *(bf16x8*)&sD[r][col];
        bf16x8 ov;
#pragma unroll
        for (int j = 0; j < 8; ++j) {
            const float z = (float)zv[j];
            ov[j] = (bf16)((float)yv[j] * (z / (1.f + __expf(-z))));
        }
        *(bf16x8*)&xzb[grow * NXZ + e0 + col] = ov;
    }
}

// ============================================================================
extern "C" void kernel_launch(void* const* d_in, const int* in_sizes, int n_in,
                              void* d_out, int out_size, void* d_ws, size_t ws_size,
                              hipStream_t stream)
{
    const float* x          = (const float*)d_in[0];
    const float* in_proj_w  = (const float*)d_in[1];
    const float* conv_w     = (const float*)d_in[2];
    const float* conv_b     = (const float*)d_in[3];
    const float* x_proj_w   = (const float*)d_in[4];
    const float* dt_proj_w  = (const float*)d_in[5];
    const float* dt_proj_b  = (const float*)d_in[6];
    const float* A_log      = (const float*)d_in[7];
    const float* Dp         = (const float*)d_in[8];
    const float* out_proj_w = (const float*)d_in[9];
    float* out = (float*)d_out;

    bf16* xzb   = (bf16*)d_ws;
    bf16* ub    = xzb   + (size_t)M * NXZ;
    bf16* xdb   = ub    + (size_t)M * DI;
    bf16* xb    = xdb   + (size_t)M * NXD;
    bf16* wbin  = xb    + (size_t)M * DM;
    bf16* wbout = wbin  + (size_t)NXZ * DM;
    bf16* wbxp  = wbout + (size_t)DM * DI;
    bf16* wbdt  = wbxp  + (size_t)NXD * DI;
    float* Pend = (float*)(wbdt + (size_t)DI * DTR);
    float* Qend = Pend + (size_t)NC * Bsz * DI * DS;
    float* H0   = Qend + (size_t)NC * Bsz * DI * DS;
    float* xpart = Pend;

    const dim3 blk(256);

    // 0. fused cast of all inputs/weights to bf16
    cast_all<<<dim3(C4 / 256), blk, 0, stream>>>(
        x, in_proj_w, out_proj_w, x_proj_w, dt_proj_w,
        xb, wbin, wbout, wbxp, wbdt);

    // 1. in_proj: xz = x @ in_proj_w^T  [4096, 4096] — 256² 8-phase kernel
    gemm256_inproj<<<dim3(256), dim3(512), 0, stream>>>(xb, wbin, xzb);

    // 2. causal conv + SiLU -> u bf16
    conv_silu<<<dim3(M * (DI / 8) / 256), blk, 0, stream>>>(xzb, conv_w, conv_b, ub);

    // 3. x_dbl = u @ x_proj_w^T  via split-K + reduce
    gemm_xproj<<<dim3(M / 128, KS), blk, 0, stream>>>(ub, wbxp, xpart);
    reduce_xdbl<<<dim3(M * 96 / 256), blk, 0, stream>>>(xpart, xdb);

    // 4. delta = softplus(x_dbl[:,:64] @ dt_proj_w^T + b) -> xzb cols [0,DI)
    gemm_bf16<1><<<dim3(DI / 128, M / 128), blk, 0, stream>>>(
        xdb, wbdt, dt_proj_b, nullptr, xzb, DI, DTR, NXD, NXZ);

    // 5. chunked selective scan; y (bf16) overwrites delta in xzb
    scan_pass1<<<dim3(DI / 256, NC, Bsz), blk, 0, stream>>>(xzb, ub, xdb, A_log, Pend, Qend);
    scan_pass2<<<dim3(Bsz * DI * DS / 256), blk, 0, stream>>>(Pend, Qend, H0);
    scan_pass3<<<dim3(DI / 256, NC, Bsz), blk, 0, stream>>>(xzb, ub, xdb, A_log, Dp, H0);

    // 6. out = x + y @ out_proj_w^T  [4096, 1024] fp32 — 4-deep ring
    gemm_out<<<dim3(512), blk, 0, stream>>>(xzb, wbout, x, out);
}